// Round 16
// baseline (6007.898 us; speedup 1.0000x reference)
//
#include <hip/hip_runtime.h>

typedef unsigned int u32;
typedef unsigned long long u64;
typedef unsigned short u16;
typedef __attribute__((ext_vector_type(8))) short short8;
typedef __attribute__((ext_vector_type(4))) float f32x4;
typedef __attribute__((ext_vector_type(4))) unsigned int u32x4;

#define MFMA(a,b,c) __builtin_amdgcn_mfma_f32_16x16x32_bf16((a),(b),(c),0,0,0)
// Agent-scope (LLC) primitives — proven R3/R10/R12 path.
#define ALOAD32(p)    __hip_atomic_load((p), __ATOMIC_RELAXED, __HIP_MEMORY_SCOPE_AGENT)
#define ASTORE32(p,v) __hip_atomic_store((p),(v), __ATOMIC_RELAXED, __HIP_MEMORY_SCOPE_AGENT)

__device__ __forceinline__ float bf2f(u32 b){ union{u32 u; float f;} v; v.u = b<<16; return v.f; }
__device__ __forceinline__ u16 f2bf(float f){ union{float f; u32 u;} v; v.f = f; u32 u = v.u;
  return (u16)((u + 0x7fffu + ((u>>16)&1u)) >> 16); }
__device__ __forceinline__ u32 pack_f(float v){
  u16 hi = f2bf(v); u16 lo = f2bf(v - bf2f(hi)); return (u32)hi | ((u32)lo<<16); }

__device__ __forceinline__ void unpack8(uint4 a, uint4 b, short8& hi, short8& lo){
  u32 w[8] = {a.x,a.y,a.z,a.w,b.x,b.y,b.z,b.w};
#pragma unroll
  for (int j=0;j<8;++j){ hi[j] = (short)(w[j] & 0xffffu); lo[j] = (short)(w[j] >> 16); }
}
// one u32x4 (16 B) = 8 consecutive bf16 of the hi-only h plane
__device__ __forceinline__ void unpackh4(u32x4 a, short8& hi){
#pragma unroll
  for (int i=0;i<4;++i){ hi[2*i] = (short)(a[i] & 0xffffu); hi[2*i+1] = (short)(a[i] >> 16); }
}

// ---------------- workspace layout (bytes) ----------------
constexpr size_t OFF_Y    = 0;            // u32[1000][32][256]; reused as out2 [250][32][1024]
constexpr size_t OFF_SUB  = 32768000;     // u32[250][32][1024]
constexpr size_t OFF_W0IH = 65536000;     // L0 image hi: 64 x 61440 u16 = 7,864,320 B
constexpr size_t OFF_W0IL = 73400320;     // L0 image lo
constexpr size_t OFF_W1IH = 81264640;     // L1 image hi: 128 x 49152 u16 = 12,582,912 B
constexpr size_t OFF_W1IL = 93847552;     // L1 image lo
constexpr size_t OFF_HB0  = 106430464;    // L0: u32[2 slot][4 grp][8][512] = 131072 B
constexpr size_t OFF_HB1  = 106692608;    // L1: u32[2 slot][2 grp][16][512] = 131072 B
constexpr size_t OFF_FL0  = 106954752;    // int[256] pad 1KB (grp g: [g*64,g*64+64))
constexpr size_t OFF_FL1  = 106955776;    // int[256] (grp g: [g*128,g*128+128))
constexpr size_t WS_NEED  = 106956800;

// ---------------- L0 weight image builder: 16 units/image, 64 images (R14-verified) ----------------
__global__ void build_w0img(const float* __restrict__ w0x, const float* __restrict__ w0h,
                            u16* __restrict__ imgH, u16* __restrict__ imgL){
  for (size_t i = (size_t)blockIdx.x*blockDim.x + threadIdx.x; i < 64ull*61440ull;
       i += (size_t)gridDim.x*blockDim.x){
    int wid = (int)(i / 61440), e = (int)(i % 61440);
    int e2, colbase; const float* src;
    if      (e < 4096) { e2 = e;         colbase = 0;    src = w0x; }
    else if (e < 8192) { e2 = e - 4096;  colbase = 1024; src = w0x; }
    else if (e < 24576){ e2 = e - 8192;  colbase = 0;    src = w0h; }
    else if (e < 40960){ e2 = e - 24576; colbase = 1024; src = w0h; }
    else if (e < 45056){ e2 = e - 40960; colbase = 2048; src = w0x; }
    else               { e2 = e - 45056; colbase = 2048; src = w0h; }
    int blk = e2 >> 9, r = e2 & 511;
    int kseg = r >> 7, c = (r >> 3) & 15, j = r & 7;
    int k = blk*32 + kseg*8 + j;
    int col = colbase + wid*16 + c;
    float v = src[(size_t)k*3072 + col];
    u16 hi = f2bf(v);
    imgH[i] = hi; imgL[i] = f2bf(v - bf2f(hi));
  }
}

// ---------------- L1 weight image builder: 8 units/image, 128 images (R15-verified) ----------------
__global__ void build_w1img(const float* __restrict__ w1x, const float* __restrict__ w1h,
                            u16* __restrict__ imgH, u16* __restrict__ imgL){
  for (size_t i = (size_t)blockIdx.x*blockDim.x + threadIdx.x; i < 128ull*49152ull;
       i += (size_t)gridDim.x*blockDim.x){
    int wid = (int)(i / 49152), e = (int)(i % 49152);
    int rg = e >> 14, e2 = e & 16383;
    int blk = e2 >> 9, rr = e2 & 511;
    int kseg = rr >> 7, c = (rr >> 3) & 15, j = rr & 7;
    int k = blk*32 + kseg*8 + j;
    const float* src; int col;
    if (rg == 0){ src = w1x; col = (c<8) ? (wid*8+c) : (1024 + wid*8 + c-8); }
    else if (rg == 1){ src = w1h; col = (c<8) ? (wid*8+c) : (1024 + wid*8 + c-8); }
    else { col = 2048 + wid*8 + ((c<8) ? c : c-8); src = (c<8) ? w1x : w1h; }
    float v = src[(size_t)k*3072 + col];
    u16 hi = f2bf(v);
    imgH[i] = hi; imgL[i] = f2bf(v - bf2f(hi));
  }
}

// ---------------- init h0 + flags (bf16-hi pairs packed in u32) ----------------
__global__ void init_state(const float* __restrict__ h0, u32* hb0, u32* hb1,
                           int* f0, int* f1){
  int i = blockIdx.x*blockDim.x + threadIdx.x;
  if (i < 256){ f0[i]=0; f1[i]=0; }
  if (i < 16384){
    int p = i & 511;
    u32 v = (u32)f2bf(h0[2*p]) | ((u32)f2bf(h0[2*p+1]) << 16);
    hb0[i] = v;
    hb1[i] = 0u;
  }
}

// ---------------- conv + relu + pack ----------------
__global__ void conv_pack(const float* __restrict__ x, const float* __restrict__ cw,
                          u32* __restrict__ yp){
  for (size_t i = (size_t)blockIdx.x*blockDim.x + threadIdx.x; i < 8192000ull;
       i += (size_t)gridDim.x*blockDim.x){
    int f = (int)(i & 255); int b = (int)((i>>8)&31); int t = (int)(i>>13);
    const float* xb = x + ((size_t)b*1000 + t)*256 + f;
    float acc = xb[0]*cw[256+f];
    if (t > 0)   acc += xb[-256]*cw[f];
    if (t < 999) acc += xb[256]*cw[512+f];
    acc = fmaxf(acc, 0.0f);
    yp[i] = pack_f(acc);
  }
}

// hready index map (both GRU kernels):
//  [0]  = K-half A h-ready step      [16] = K-half B h-ready step
//  [8]  = wave0 exch-read-done step  [24] = wave1 exch-read-done step (init -1)
//  [25] = wave1 h-store-ack step (init -1)
#define HREADY_INIT(idx) ((idx)==8 || (idx)==24 || (idx)==25 ? -1 : 0)

// ---------------- L0 4-group sample-split GRU (R14 math + S2-free handshake) ----------------
__global__ __launch_bounds__(512, 1)
void gru16_persist(const u32* __restrict__ xin,
                   const u16* __restrict__ imgH, const u16* __restrict__ imgL,
                   const float* __restrict__ bias,
                   u32* hbuf, int* flags, u32* out_pack)
{
  __shared__ u16 WIMG[61440];
  __shared__ float exch[8*8*66];
  __shared__ float harr[128];
  __shared__ int hready[32];

  const int tid  = threadIdx.x;
  const int wg   = blockIdx.x;
  const int g    = wg >> 6;
  const int wid  = wg & 63;
  const int lane = tid & 63;
  const int wave = tid >> 6;
  const int kq   = wave;
  const int lo16 = lane & 15, hi16 = lane >> 4;
  const int lane_off = hi16*128 + lo16*8;
  const int hsel = (kq >= 4) ? 16 : 0;
  const int srow = lo16 & 7;
  volatile int* vh = (volatile int*)hready;

  {
    const u64* sH = (const u64*)(imgH + (size_t)wid*61440);
    u64* dH = (u64*)WIMG;
    for (int i = tid; i < 15360; i += 512) dH[i] = sH[i];
    if (tid < 32) hready[tid] = HREADY_INIT(tid);
    if (tid < 128){
      u16 hv = ((const u16*)hbuf)[g*8192 + (tid>>4)*1024 + wid*16 + (tid&15)];
      harr[tid] = bf2f((u32)hv);
    }
  }
  __syncthreads();

  const u16* gLo  = imgL + (size_t)wid*61440;
  const u16* zx_h = &WIMG[kq*512 + lane_off];          const u16* zx_l = gLo + kq*512 + lane_off;
  const u16* rx_h = &WIMG[4096 + kq*512 + lane_off];   const u16* rx_l = gLo + 4096 + kq*512 + lane_off;
  const u16* zh_h = &WIMG[8192 + kq*2048 + lane_off];  const u16* zh_l = gLo + 8192 + kq*2048 + lane_off;
  const u16* rh_h = &WIMG[24576 + kq*2048 + lane_off]; const u16* rh_l = gLo + 24576 + kq*2048 + lane_off;
  const u16* xh_h = &WIMG[40960 + kq*512 + lane_off];  const u16* xh_l = gLo + 40960 + kq*512 + lane_off;
  const u16* hh_h = &WIMG[45056 + kq*2048 + lane_off]; const u16* hh_l = gLo + 45056 + kq*2048 + lane_off;

  const int gs = tid >> 4, gu = tid & 15, eu = wid*16 + gu;
  const float zb  = bias[eu]        + bias[3072 + eu];
  const float rbv = bias[1024 + eu] + bias[4096 + eu];
  const float hxb = bias[2048 + eu];
  const float hrb = bias[5120 + eu];

  for (int t = 0; t < 1000; ++t) {
    const int cur = t & 1, nxt = cur ^ 1;
    f32x4 aZ  = (f32x4){0.f,0.f,0.f,0.f};
    f32x4 aR  = (f32x4){0.f,0.f,0.f,0.f};
    f32x4 aHX = (f32x4){0.f,0.f,0.f,0.f};
    f32x4 aHR = (f32x4){0.f,0.f,0.f,0.f};
    { // x-pass
      const u32* xr = xin + ((size_t)t*32 + g*8 + srow)*256 + kq*32 + hi16*8;
      uint4 a0 = *(const uint4*)xr;
      uint4 a1 = *(const uint4*)(xr + 4);
      short8 ahi, alo; unpack8(a0, a1, ahi, alo);
      short8 bzh = *(const short8*)zx_h, bzl = *(const short8*)zx_l;
      short8 brh = *(const short8*)rx_h, brl = *(const short8*)rx_l;
      short8 bxh = *(const short8*)xh_h, bxl = *(const short8*)xh_l;
      aZ  = MFMA(ahi,bzh,aZ);  aZ  = MFMA(alo,bzh,aZ);  aZ  = MFMA(ahi,bzl,aZ);
      aR  = MFMA(ahi,brh,aR);  aR  = MFMA(alo,brh,aR);  aR  = MFMA(ahi,brl,aR);
      aHX = MFMA(ahi,bxh,aHX); aHX = MFMA(alo,bxh,aHX); aHX = MFMA(ahi,bxl,aHX);
    }
    if (t > 0) { // split-release h wait
      if (wave == 0) {
        int f0;
        do { f0 = ALOAD32(flags + g*64 + (lane & 31)); } while (__all(f0 >= t) == 0);
        asm volatile("" ::: "memory");
        if (lane == 0) vh[0] = t;
      } else if (wave == 1) {
        int f1;
        do { f1 = ALOAD32(flags + g*64 + 32 + (lane & 31)); } while (__all(f1 >= t) == 0);
        asm volatile("" ::: "memory");
        if (lane == 0) vh[16] = t;
      }
      while (vh[hsel] < t) { }
      asm volatile("" ::: "memory");
    }
    { // h-pass
      const u32* hrow = hbuf + cur*16384 + g*4096 + srow*512 + kq*64 + hi16*4;
      u32x4 qa, qb, qc, qd;
      asm volatile(
        "global_load_dwordx4 %0, %4, off sc0 sc1\n\t"
        "global_load_dwordx4 %1, %4, off offset:64 sc0 sc1\n\t"
        "global_load_dwordx4 %2, %4, off offset:128 sc0 sc1\n\t"
        "global_load_dwordx4 %3, %4, off offset:192 sc0 sc1\n\t"
        "s_waitcnt vmcnt(0)"
        : "=&v"(qa), "=&v"(qb), "=&v"(qc), "=&v"(qd)
        : "v"(hrow)
        : "memory");
      short8 ah0, ah1, ah2, ah3;
      unpackh4(qa, ah0); unpackh4(qb, ah1); unpackh4(qc, ah2); unpackh4(qd, ah3);
#pragma unroll
      for (int kt = 0; kt < 4; ++kt){
        short8 ah = (kt==0)?ah0:(kt==1)?ah1:(kt==2)?ah2:ah3;
        short8 bzh = *(const short8*)(zh_h + kt*512), bzl = *(const short8*)(zh_l + kt*512);
        short8 brh = *(const short8*)(rh_h + kt*512), brl = *(const short8*)(rh_l + kt*512);
        short8 bhh = *(const short8*)(hh_h + kt*512), bhl = *(const short8*)(hh_l + kt*512);
        aZ  = MFMA(ah,bzh,aZ);  aZ  = MFMA(ah,bzl,aZ);
        aR  = MFMA(ah,brh,aR);  aR  = MFMA(ah,brl,aR);
        aHR = MFMA(ah,bhh,aHR); aHR = MFMA(ah,bhl,aHR);
      }
    }
    // exch(t) writes must wait until gates(t-1) finished READING exch.
    while (vh[8] < t-1 || vh[24] < t-1) { }
    asm volatile("" ::: "memory");
    {
      if (hi16 < 2) {
#pragma unroll
        for (int r4 = 0; r4 < 4; ++r4){
          float* e = &exch[(kq*8 + hi16*4 + r4)*66];
          e[lo16]      = aZ[r4];
          e[16 + lo16] = aR[r4];
          e[32 + lo16] = aHX[r4];
          e[48 + lo16] = aHR[r4];
        }
      }
    }
    __syncthreads();                       // S1: exch(t) visible; joins all waves
    if (tid < 128) { // gates in waves 0-1 only; publish without S2
      float zp=0.f, rp=0.f, xh=0.f, rh=0.f;
#pragma unroll
      for (int k8 = 0; k8 < 8; ++k8){
        const float* e = &exch[(k8*8 + gs)*66];
        zp += e[gu]; rp += e[16+gu]; xh += e[32+gu]; rh += e[48+gu];
      }
      asm volatile("" ::: "memory");
      if (tid == 0)  vh[8]  = t;           // wave0 done reading exch
      if (tid == 64) vh[24] = t;           // wave1 done reading exch
      float z = 1.f/(1.f + __expf(-(zp + zb)));
      float r = 1.f/(1.f + __expf(-(rp + rbv)));
      float pre = xh + hxb + r*(rh + hrb);
      float ex = __expf(-2.f*fabsf(pre));
      float th = (1.f - ex)/(1.f + ex);
      float hh = copysignf(th, pre);
      float hn = z*harr[tid] + (1.f - z)*hh;
      harr[tid] = hn;
      u32 pk_out = pack_f(hn);
      int pk16 = (int)(pk_out & 0xffffu);
      int prt  = __shfl_xor(pk16, 1);
      if ((tid & 1) == 0) {
        u32 pair = (u32)pk16 | ((u32)prt << 16);
        ASTORE32(hbuf + nxt*16384 + g*4096 + gs*512 + wid*8 + (gu>>1), pair);
      }
      asm volatile("s_waitcnt vmcnt(0)" ::: "memory");   // own wave's h stores acked
      if (tid == 64) vh[25] = t;                         // wave1 ack
      if (tid == 0) {
        while (vh[25] < t) { }                           // wait wave1 ack
        ASTORE32(flags + g*64 + wid, t+1);               // publish immediately
      }
      if ((t & 3) == 0)                                  // off-path sub_pack store
        out_pack[((size_t)(t>>2)*32 + g*8 + gs)*1024 + eu] = pk_out;
    }
  }
}

// ---------------- L1 2-group sample-split GRU (R15 math + S2-free handshake) ----------------
__global__ __launch_bounds__(512, 1)
void gru8L1_persist(const u32* __restrict__ xin,
                    const u16* __restrict__ imgH, const u16* __restrict__ imgL,
                    const float* __restrict__ bias,
                    u32* hbuf, int* flags, u32* out_pack)
{
  __shared__ u16 WIMG[49152];
  __shared__ float exch[8*16*33];
  __shared__ float harr[128];
  __shared__ int hready[32];

  const int tid  = threadIdx.x;
  const int wg   = blockIdx.x;
  const int g    = wg >> 7;
  const int wid  = wg & 127;
  const int lane = tid & 63;
  const int wave = tid >> 6;
  const int kq   = wave;
  const int lo16 = lane & 15, hi16 = lane >> 4;
  const int lane_off = hi16*128 + lo16*8;
  const int hsel = (kq >= 4) ? 16 : 0;
  volatile int* vh = (volatile int*)hready;

  {
    const u64* sH = (const u64*)(imgH + (size_t)wid*49152);
    u64* dH = (u64*)WIMG;
    for (int i = tid; i < 12288; i += 512) dH[i] = sH[i];
    if (tid < 32) hready[tid] = HREADY_INIT(tid);
    if (tid < 128){
      u16 hv = ((const u16*)hbuf)[g*16384 + (tid>>3)*1024 + wid*8 + (tid&7)];
      harr[tid] = bf2f((u32)hv);
    }
  }
  __syncthreads();

  const u16* gLo   = imgL + (size_t)wid*49152;
  const u16* zrx_h = &WIMG[kq*2048 + lane_off];          const u16* zrx_l = gLo + kq*2048 + lane_off;
  const u16* zrh_h = &WIMG[16384 + kq*2048 + lane_off];  const u16* zrh_l = gLo + 16384 + kq*2048 + lane_off;
  const u16* xhh_h = &WIMG[32768 + kq*2048 + lane_off];  const u16* xhh_l = gLo + 32768 + kq*2048 + lane_off;

  const int gs = tid >> 3, gu = tid & 7, eu = wid*8 + gu;
  const float zb  = bias[eu]        + bias[3072 + eu];
  const float rbv = bias[1024 + eu] + bias[4096 + eu];
  const float hxb = bias[2048 + eu];
  const float hrb = bias[5120 + eu];

  for (int t = 0; t < 250; ++t) {
    const int cur = t & 1, nxt = cur ^ 1;
    f32x4 aZR = (f32x4){0.f,0.f,0.f,0.f};
    f32x4 aXH = (f32x4){0.f,0.f,0.f,0.f};
    f32x4 aHR = (f32x4){0.f,0.f,0.f,0.f};
    { // x-pass
      const u32* xrow = xin + ((size_t)t*32 + g*16 + lo16)*1024 + kq*128 + hi16*8;
#pragma unroll
      for (int kt = 0; kt < 4; ++kt) {
        uint4 a0 = *(const uint4*)(xrow + kt*32);
        uint4 a1 = *(const uint4*)(xrow + kt*32 + 4);
        short8 ahi, alo; unpack8(a0, a1, ahi, alo);
        short8 bzh = *(const short8*)(zrx_h + kt*512), bzl = *(const short8*)(zrx_l + kt*512);
        short8 bxh = *(const short8*)(xhh_h + kt*512), bxl = *(const short8*)(xhh_l + kt*512);
        aZR = MFMA(ahi,bzh,aZR); aZR = MFMA(alo,bzh,aZR); aZR = MFMA(ahi,bzl,aZR);
        aXH = MFMA(ahi,bxh,aXH); aXH = MFMA(alo,bxh,aXH); aXH = MFMA(ahi,bxl,aXH);
      }
    }
    if (t > 0) {
      if (wave == 0) {
        int f0;
        do { f0 = ALOAD32(flags + g*128 + lane); } while (__all(f0 >= t) == 0);
        asm volatile("" ::: "memory");
        if (lane == 0) vh[0] = t;
      } else if (wave == 1) {
        int f1;
        do { f1 = ALOAD32(flags + g*128 + 64 + lane); } while (__all(f1 >= t) == 0);
        asm volatile("" ::: "memory");
        if (lane == 0) vh[16] = t;
      }
      while (vh[hsel] < t) { }
      asm volatile("" ::: "memory");
    }
    { // h-pass
      const u32* hrow = hbuf + cur*16384 + g*8192 + lo16*512 + kq*64 + hi16*4;
      u32x4 qa, qb, qc, qd;
      asm volatile(
        "global_load_dwordx4 %0, %4, off sc0 sc1\n\t"
        "global_load_dwordx4 %1, %4, off offset:64 sc0 sc1\n\t"
        "global_load_dwordx4 %2, %4, off offset:128 sc0 sc1\n\t"
        "global_load_dwordx4 %3, %4, off offset:192 sc0 sc1\n\t"
        "s_waitcnt vmcnt(0)"
        : "=&v"(qa), "=&v"(qb), "=&v"(qc), "=&v"(qd)
        : "v"(hrow)
        : "memory");
      short8 ah0, ah1, ah2, ah3;
      unpackh4(qa, ah0); unpackh4(qb, ah1); unpackh4(qc, ah2); unpackh4(qd, ah3);
#pragma unroll
      for (int kt = 0; kt < 4; ++kt){
        short8 ah = (kt==0)?ah0:(kt==1)?ah1:(kt==2)?ah2:ah3;
        short8 bzh = *(const short8*)(zrh_h + kt*512), bzl = *(const short8*)(zrh_l + kt*512);
        short8 bhh = *(const short8*)(xhh_h + kt*512), bhl = *(const short8*)(xhh_l + kt*512);
        aZR = MFMA(ah,bzh,aZR); aZR = MFMA(ah,bzl,aZR);
        aHR = MFMA(ah,bhh,aHR); aHR = MFMA(ah,bhl,aHR);
      }
    }
    while (vh[8] < t-1 || vh[24] < t-1) { }
    asm volatile("" ::: "memory");
    {
#pragma unroll
      for (int r4 = 0; r4 < 4; ++r4){
        float* e = &exch[(kq*16 + hi16*4 + r4)*33];
        e[lo16]      = aZR[r4];
        e[16 + lo16] = (lo16 < 8) ? aXH[r4] : aHR[r4];
      }
    }
    __syncthreads();                       // S1
    if (tid < 128) {
      float zp=0.f, rp=0.f, xh=0.f, rh=0.f;
#pragma unroll
      for (int k8 = 0; k8 < 8; ++k8){
        const float* e = &exch[(k8*16 + gs)*33];
        zp += e[gu]; rp += e[8+gu]; xh += e[16+gu]; rh += e[24+gu];
      }
      asm volatile("" ::: "memory");
      if (tid == 0)  vh[8]  = t;
      if (tid == 64) vh[24] = t;
      float z = 1.f/(1.f + __expf(-(zp + zb)));
      float r = 1.f/(1.f + __expf(-(rp + rbv)));
      float pre = xh + hxb + r*(rh + hrb);
      float ex = __expf(-2.f*fabsf(pre));
      float th = (1.f - ex)/(1.f + ex);
      float hh = copysignf(th, pre);
      float hn = z*harr[tid] + (1.f - z)*hh;
      harr[tid] = hn;
      u32 pk_out = pack_f(hn);
      int pk16 = (int)(pk_out & 0xffffu);
      int prt  = __shfl_xor(pk16, 1);
      if ((tid & 1) == 0) {
        u32 pair = (u32)pk16 | ((u32)prt << 16);
        ASTORE32(hbuf + nxt*16384 + g*8192 + gs*512 + wid*4 + (gu>>1), pair);
      }
      asm volatile("s_waitcnt vmcnt(0)" ::: "memory");
      if (tid == 64) vh[25] = t;
      if (tid == 0) {
        while (vh[25] < t) { }
        ASTORE32(flags + g*128 + wid, t+1);
      }
      out_pack[((size_t)t*32 + g*16 + gs)*1024 + eu] = pk_out;
    }
  }
}

// ---------------- final dense head ----------------
__global__ __launch_bounds__(256, 1)
void dense_k(const u32* __restrict__ h2, const float* __restrict__ W,
             const float* __restrict__ bias, float* __restrict__ out){
  __shared__ float rows[32*1025];
  const int ts = blockIdx.x;
  const u32* src = h2 + (size_t)ts*32768;
  for (int i = threadIdx.x; i < 32768; i += 256){
    u32 p = src[i];
    rows[(i>>10)*1025 + (i&1023)] = bf2f(p & 0xffffu) + bf2f(p >> 16);
  }
  __syncthreads();
  const int b = threadIdx.x >> 3, cg = threadIdx.x & 7;
  float acc[6] = {0.f,0.f,0.f,0.f,0.f,0.f};
  for (int k = 0; k < 1024; ++k){
    float hv = rows[b*1025 + k];
    const float* wr = W + k*41;
#pragma unroll
    for (int j = 0; j < 6; ++j){ int c = cg + 8*j; if (c < 41) acc[j] += hv*wr[c]; }
  }
#pragma unroll
  for (int j = 0; j < 6; ++j){
    int c = cg + 8*j;
    if (c < 41) out[((size_t)b*250 + ts)*41 + c] = acc[j] + bias[c];
  }
}

// ---------------- launch ----------------
extern "C" void kernel_launch(void* const* d_in, const int* in_sizes, int n_in,
                              void* d_out, int out_size, void* d_ws, size_t ws_size,
                              hipStream_t stream) {
  const float* x      = (const float*)d_in[0];
  const float* conv_w = (const float*)d_in[1];
  const float* h0i    = (const float*)d_in[2];
  const float* w0x    = (const float*)d_in[3];
  const float* w0h    = (const float*)d_in[4];
  const float* b0     = (const float*)d_in[5];
  const float* w1x    = (const float*)d_in[6];
  const float* w1h    = (const float*)d_in[7];
  const float* b1     = (const float*)d_in[8];
  const float* dw     = (const float*)d_in[9];
  const float* db     = (const float*)d_in[10];
  float* outp = (float*)d_out;

  if (ws_size < WS_NEED) return;  // workspace too small: leave output poisoned

  char* ws = (char*)d_ws;
  u32* y_pack   = (u32*)(ws + OFF_Y);
  u32* out2     = (u32*)(ws + OFF_Y);      // reuse after y_pack is dead
  u32* sub_pack = (u32*)(ws + OFF_SUB);
  u16* w0iH = (u16*)(ws + OFF_W0IH); u16* w0iL = (u16*)(ws + OFF_W0IL);
  u16* w1iH = (u16*)(ws + OFF_W1IH); u16* w1iL = (u16*)(ws + OFF_W1IL);
  u32* hb0 = (u32*)(ws + OFF_HB0);
  u32* hb1 = (u32*)(ws + OFF_HB1);
  int* fl0 = (int*)(ws + OFF_FL0);
  int* fl1 = (int*)(ws + OFF_FL1);

  init_state<<<64, 512, 0, stream>>>(h0i, hb0, hb1, fl0, fl1);
  build_w0img<<<2048, 256, 0, stream>>>(w0x, w0h, w0iH, w0iL);
  build_w1img<<<2048, 256, 0, stream>>>(w1x, w1h, w1iH, w1iL);
  conv_pack<<<4096, 256, 0, stream>>>(x, conv_w, y_pack);

  gru16_persist<<<256, 512, 0, stream>>>(y_pack, w0iH, w0iL, b0, hb0, fl0, sub_pack);
  gru8L1_persist<<<256, 512, 0, stream>>>(sub_pack, w1iH, w1iL, b1, hb1, fl1, out2);

  dense_k<<<250, 256, 0, stream>>>(out2, dw, db, outp);
}

// Round 17
// 5427.412 us; speedup vs baseline: 1.1070x; 1.1070x over previous
//
#include <hip/hip_runtime.h>

typedef unsigned int u32;
typedef unsigned long long u64;
typedef unsigned short u16;
typedef __attribute__((ext_vector_type(8))) short short8;
typedef __attribute__((ext_vector_type(4))) float f32x4;
typedef __attribute__((ext_vector_type(4))) unsigned int u32x4;

#define MFMA(a,b,c) __builtin_amdgcn_mfma_f32_16x16x32_bf16((a),(b),(c),0,0,0)
// Agent-scope (LLC) primitives — proven R3/R10/R12 path.
#define ALOAD32(p)    __hip_atomic_load((p), __ATOMIC_RELAXED, __HIP_MEMORY_SCOPE_AGENT)
#define ASTORE32(p,v) __hip_atomic_store((p),(v), __ATOMIC_RELAXED, __HIP_MEMORY_SCOPE_AGENT)

__device__ __forceinline__ float bf2f(u32 b){ union{u32 u; float f;} v; v.u = b<<16; return v.f; }
__device__ __forceinline__ u16 f2bf(float f){ union{float f; u32 u;} v; v.f = f; u32 u = v.u;
  return (u16)((u + 0x7fffu + ((u>>16)&1u)) >> 16); }
__device__ __forceinline__ u32 pack_f(float v){
  u16 hi = f2bf(v); u16 lo = f2bf(v - bf2f(hi)); return (u32)hi | ((u32)lo<<16); }

__device__ __forceinline__ void unpack8(uint4 a, uint4 b, short8& hi, short8& lo){
  u32 w[8] = {a.x,a.y,a.z,a.w,b.x,b.y,b.z,b.w};
#pragma unroll
  for (int j=0;j<8;++j){ hi[j] = (short)(w[j] & 0xffffu); lo[j] = (short)(w[j] >> 16); }
}
// one u32x4 (16 B) = 8 consecutive bf16 of the hi-only h plane
__device__ __forceinline__ void unpackh4(u32x4 a, short8& hi){
#pragma unroll
  for (int i=0;i<4;++i){ hi[2*i] = (short)(a[i] & 0xffffu); hi[2*i+1] = (short)(a[i] >> 16); }
}

// ---------------- workspace layout (bytes) ----------------
constexpr size_t OFF_Y    = 0;            // u32[1000][32][256]; reused as out2 [250][32][1024]
constexpr size_t OFF_SUB  = 32768000;     // u32[250][32][1024]
constexpr size_t OFF_W0IH = 65536000;     // L0 image hi: 64 x 61440 u16 = 7,864,320 B
constexpr size_t OFF_W0IL = 73400320;     // L0 image lo
constexpr size_t OFF_W1IH = 81264640;     // L1 image hi: 128 x 49152 u16 = 12,582,912 B
constexpr size_t OFF_W1IL = 93847552;     // L1 image lo
constexpr size_t OFF_HB0  = 106430464;    // L0: u32[2 slot][4 grp][8][512] = 131072 B
constexpr size_t OFF_HB1  = 106692608;    // L1: u32[2 slot][2 grp][16][512] = 131072 B
constexpr size_t OFF_FL0  = 106954752;    // int[256] pad 1KB (grp g: [g*64,g*64+64))
constexpr size_t OFF_FL1  = 106955776;    // int[256] (grp g: [g*128,g*128+128))
constexpr size_t WS_NEED  = 106956800;

// ---------------- L0 weight image builder: 16 units/image, 64 images (R14-verified) ----------------
// Per-image u16 plane = 61440 elems, SIX plain full-16-col regions:
//   [0,4096) ZX | [4096,8192) RX | [8192,24576) ZH | [24576,40960) RH
//   [40960,45056) XH | [45056,61440) HH
// block elem: r=e&511, kseg=r>>7, c=(r>>3)&15, j=r&7; k=blk*32+kseg*8+j
__global__ void build_w0img(const float* __restrict__ w0x, const float* __restrict__ w0h,
                            u16* __restrict__ imgH, u16* __restrict__ imgL){
  for (size_t i = (size_t)blockIdx.x*blockDim.x + threadIdx.x; i < 64ull*61440ull;
       i += (size_t)gridDim.x*blockDim.x){
    int wid = (int)(i / 61440), e = (int)(i % 61440);
    int e2, colbase; const float* src;
    if      (e < 4096) { e2 = e;         colbase = 0;    src = w0x; }
    else if (e < 8192) { e2 = e - 4096;  colbase = 1024; src = w0x; }
    else if (e < 24576){ e2 = e - 8192;  colbase = 0;    src = w0h; }
    else if (e < 40960){ e2 = e - 24576; colbase = 1024; src = w0h; }
    else if (e < 45056){ e2 = e - 40960; colbase = 2048; src = w0x; }
    else               { e2 = e - 45056; colbase = 2048; src = w0h; }
    int blk = e2 >> 9, r = e2 & 511;
    int kseg = r >> 7, c = (r >> 3) & 15, j = r & 7;
    int k = blk*32 + kseg*8 + j;
    int col = colbase + wid*16 + c;
    float v = src[(size_t)k*3072 + col];
    u16 hi = f2bf(v);
    imgH[i] = hi; imgL[i] = f2bf(v - bf2f(hi));
  }
}

// ---------------- L1 weight image builder: 8 units/image, 128 images, FUSED 16-col tiles ----------------
// Per-image u16 plane = 49152 elems, THREE K=1024 regions of 16384:
//   [0,16384)      ZRX: [Wxz8|Wxr8]   (src w1x)
//   [16384,32768)  ZRH: [Whz8|Whr8]   (src w1h)
//   [32768,49152)  XHH: [Wxh8|Whh8]   (c<8: w1x, c>=8: w1h)
// block elem: rr=e2&511, kseg=rr>>7, c=(rr>>3)&15, j=rr&7; k=blk*32+kseg*8+j
__global__ void build_w1img(const float* __restrict__ w1x, const float* __restrict__ w1h,
                            u16* __restrict__ imgH, u16* __restrict__ imgL){
  for (size_t i = (size_t)blockIdx.x*blockDim.x + threadIdx.x; i < 128ull*49152ull;
       i += (size_t)gridDim.x*blockDim.x){
    int wid = (int)(i / 49152), e = (int)(i % 49152);
    int rg = e >> 14, e2 = e & 16383;
    int blk = e2 >> 9, rr = e2 & 511;
    int kseg = rr >> 7, c = (rr >> 3) & 15, j = rr & 7;
    int k = blk*32 + kseg*8 + j;
    const float* src; int col;
    if (rg == 0){ src = w1x; col = (c<8) ? (wid*8+c) : (1024 + wid*8 + c-8); }
    else if (rg == 1){ src = w1h; col = (c<8) ? (wid*8+c) : (1024 + wid*8 + c-8); }
    else { col = 2048 + wid*8 + ((c<8) ? c : c-8); src = (c<8) ? w1x : w1h; }
    float v = src[(size_t)k*3072 + col];
    u16 hi = f2bf(v);
    imgH[i] = hi; imgL[i] = f2bf(v - bf2f(hi));
  }
}

// ---------------- init h0 + flags (bf16-hi pairs packed in u32) ----------------
__global__ void init_state(const float* __restrict__ h0, u32* hb0, u32* hb1,
                           int* f0, int* f1){
  int i = blockIdx.x*blockDim.x + threadIdx.x;
  if (i < 256){ f0[i]=0; f1[i]=0; }
  if (i < 16384){   // slot 0. L0: [4grp][8row][512]; L1: [2grp][16row][512] — pair = i&511
    int p = i & 511;
    u32 v = (u32)f2bf(h0[2*p]) | ((u32)f2bf(h0[2*p+1]) << 16);
    hb0[i] = v;
    hb1[i] = 0u;
  }
}

// ---------------- conv + relu + pack ----------------
__global__ void conv_pack(const float* __restrict__ x, const float* __restrict__ cw,
                          u32* __restrict__ yp){
  for (size_t i = (size_t)blockIdx.x*blockDim.x + threadIdx.x; i < 8192000ull;
       i += (size_t)gridDim.x*blockDim.x){
    int f = (int)(i & 255); int b = (int)((i>>8)&31); int t = (int)(i>>13);
    const float* xb = x + ((size_t)b*1000 + t)*256 + f;
    float acc = xb[0]*cw[256+f];
    if (t > 0)   acc += xb[-256]*cw[f];
    if (t < 999) acc += xb[256]*cw[512+f];
    acc = fmaxf(acc, 0.0f);
    yp[i] = pack_f(acc);
  }
}

// ---------------- L0 4-group sample-split GRU: 256 WGs x 512 thr, 16 units/WG ----------------
// Group g=wg>>6 owns samples [g*8,g*8+8); wid=wg&63 owns units [wid*16,wid*16+16).
// Per-WG h ingest = 16 KB/step -> aggregate 4 MB/step.
// MFMA A rows 8-15 duplicate rows 0-7 (coalesced; results discarded).
// hi weight plane (120 KB) in LDS; lo plane read from global (L2-resident).
// Sync = R12/R13-verified: wave0/1 K-half flag poll -> LDS release; S1/S2; pair-
// packed bf16-hi publish; off-path sub_pack store.
__global__ __launch_bounds__(512, 1)
void gru16_persist(const u32* __restrict__ xin,
                   const u16* __restrict__ imgH, const u16* __restrict__ imgL,
                   const float* __restrict__ bias,
                   u32* hbuf, int* flags, u32* out_pack)
{
  __shared__ u16 WIMG[61440];        // hi plane, 122,880 B
  __shared__ float exch[8*8*66];     // 16,896 B
  __shared__ float harr[128];
  __shared__ int hready[32];

  const int tid  = threadIdx.x;
  const int wg   = blockIdx.x;
  const int g    = wg >> 6;
  const int wid  = wg & 63;
  const int lane = tid & 63;
  const int wave = tid >> 6;
  const int kq   = wave;
  const int lo16 = lane & 15, hi16 = lane >> 4;
  const int lane_off = hi16*128 + lo16*8;
  const int hsel = (kq >= 4) ? 16 : 0;
  const int srow = lo16 & 7;

  {
    const u64* sH = (const u64*)(imgH + (size_t)wid*61440);
    u64* dH = (u64*)WIMG;
    for (int i = tid; i < 15360; i += 512) dH[i] = sH[i];
    if (tid < 32) hready[tid] = 0;
    if (tid < 128){
      u16 hv = ((const u16*)hbuf)[g*8192 + (tid>>4)*1024 + wid*16 + (tid&15)];
      harr[tid] = bf2f((u32)hv);
    }
  }
  __syncthreads();

  const u16* gLo  = imgL + (size_t)wid*61440;
  const u16* zx_h = &WIMG[kq*512 + lane_off];          const u16* zx_l = gLo + kq*512 + lane_off;
  const u16* rx_h = &WIMG[4096 + kq*512 + lane_off];   const u16* rx_l = gLo + 4096 + kq*512 + lane_off;
  const u16* zh_h = &WIMG[8192 + kq*2048 + lane_off];  const u16* zh_l = gLo + 8192 + kq*2048 + lane_off;
  const u16* rh_h = &WIMG[24576 + kq*2048 + lane_off]; const u16* rh_l = gLo + 24576 + kq*2048 + lane_off;
  const u16* xh_h = &WIMG[40960 + kq*512 + lane_off];  const u16* xh_l = gLo + 40960 + kq*512 + lane_off;
  const u16* hh_h = &WIMG[45056 + kq*2048 + lane_off]; const u16* hh_l = gLo + 45056 + kq*2048 + lane_off;

  const int gs = tid >> 4, gu = tid & 15, eu = wid*16 + gu;
  const float zb  = bias[eu]        + bias[3072 + eu];
  const float rbv = bias[1024 + eu] + bias[4096 + eu];
  const float hxb = bias[2048 + eu];
  const float hrb = bias[5120 + eu];

  for (int t = 0; t < 1000; ++t) {
    const int cur = t & 1, nxt = cur ^ 1;
    f32x4 aZ  = (f32x4){0.f,0.f,0.f,0.f};
    f32x4 aR  = (f32x4){0.f,0.f,0.f,0.f};
    f32x4 aHX = (f32x4){0.f,0.f,0.f,0.f};
    f32x4 aHR = (f32x4){0.f,0.f,0.f,0.f};
    {
      const u32* xr = xin + ((size_t)t*32 + g*8 + srow)*256 + kq*32 + hi16*8;
      uint4 a0 = *(const uint4*)xr;
      uint4 a1 = *(const uint4*)(xr + 4);
      short8 ahi, alo; unpack8(a0, a1, ahi, alo);
      short8 bzh = *(const short8*)zx_h, bzl = *(const short8*)zx_l;
      short8 brh = *(const short8*)rx_h, brl = *(const short8*)rx_l;
      short8 bxh = *(const short8*)xh_h, bxl = *(const short8*)xh_l;
      aZ  = MFMA(ahi,bzh,aZ);  aZ  = MFMA(alo,bzh,aZ);  aZ  = MFMA(ahi,bzl,aZ);
      aR  = MFMA(ahi,brh,aR);  aR  = MFMA(alo,brh,aR);  aR  = MFMA(ahi,brl,aR);
      aHX = MFMA(ahi,bxh,aHX); aHX = MFMA(alo,bxh,aHX); aHX = MFMA(ahi,bxl,aHX);
    }
    if (t > 0) {
      if (wave == 0) {
        int f0;
        do { f0 = ALOAD32(flags + g*64 + (lane & 31)); } while (__all(f0 >= t) == 0);
        asm volatile("" ::: "memory");
        if (lane == 0) ((volatile int*)hready)[0] = t;
      } else if (wave == 1) {
        int f1;
        do { f1 = ALOAD32(flags + g*64 + 32 + (lane & 31)); } while (__all(f1 >= t) == 0);
        asm volatile("" ::: "memory");
        if (lane == 0) ((volatile int*)hready)[16] = t;
      }
      while (((volatile int*)hready)[hsel] < t) { }
      asm volatile("" ::: "memory");
    }
    {
      const u32* hrow = hbuf + cur*16384 + g*4096 + srow*512 + kq*64 + hi16*4;
      u32x4 qa, qb, qc, qd;
      asm volatile(
        "global_load_dwordx4 %0, %4, off sc0 sc1\n\t"
        "global_load_dwordx4 %1, %4, off offset:64 sc0 sc1\n\t"
        "global_load_dwordx4 %2, %4, off offset:128 sc0 sc1\n\t"
        "global_load_dwordx4 %3, %4, off offset:192 sc0 sc1\n\t"
        "s_waitcnt vmcnt(0)"
        : "=&v"(qa), "=&v"(qb), "=&v"(qc), "=&v"(qd)
        : "v"(hrow)
        : "memory");
      short8 ah0, ah1, ah2, ah3;
      unpackh4(qa, ah0); unpackh4(qb, ah1); unpackh4(qc, ah2); unpackh4(qd, ah3);
#pragma unroll
      for (int kt = 0; kt < 4; ++kt){
        short8 ah = (kt==0)?ah0:(kt==1)?ah1:(kt==2)?ah2:ah3;
        short8 bzh = *(const short8*)(zh_h + kt*512), bzl = *(const short8*)(zh_l + kt*512);
        short8 brh = *(const short8*)(rh_h + kt*512), brl = *(const short8*)(rh_l + kt*512);
        short8 bhh = *(const short8*)(hh_h + kt*512), bhl = *(const short8*)(hh_l + kt*512);
        aZ  = MFMA(ah,bzh,aZ);  aZ  = MFMA(ah,bzl,aZ);
        aR  = MFMA(ah,brh,aR);  aR  = MFMA(ah,brl,aR);
        aHR = MFMA(ah,bhh,aHR); aHR = MFMA(ah,bhl,aHR);
      }
    }
    {
      if (hi16 < 2) {
#pragma unroll
        for (int r4 = 0; r4 < 4; ++r4){
          float* e = &exch[(kq*8 + hi16*4 + r4)*66];
          e[lo16]      = aZ[r4];
          e[16 + lo16] = aR[r4];
          e[32 + lo16] = aHX[r4];
          e[48 + lo16] = aHR[r4];
        }
      }
    }
    __syncthreads();
    u32 pk_out = 0;
    if (tid < 128) {
      float zp=0.f, rp=0.f, xh=0.f, rh=0.f;
#pragma unroll
      for (int k8 = 0; k8 < 8; ++k8){
        const float* e = &exch[(k8*8 + gs)*66];
        zp += e[gu]; rp += e[16+gu]; xh += e[32+gu]; rh += e[48+gu];
      }
      float z = 1.f/(1.f + __expf(-(zp + zb)));
      float r = 1.f/(1.f + __expf(-(rp + rbv)));
      float pre = xh + hxb + r*(rh + hrb);
      float ex = __expf(-2.f*fabsf(pre));
      float th = (1.f - ex)/(1.f + ex);
      float hh = copysignf(th, pre);
      float hn = z*harr[tid] + (1.f - z)*hh;
      harr[tid] = hn;
      pk_out = pack_f(hn);
      int pk16 = (int)(pk_out & 0xffffu);
      int prt  = __shfl_xor(pk16, 1);
      if ((tid & 1) == 0) {
        u32 pair = (u32)pk16 | ((u32)prt << 16);
        ASTORE32(hbuf + nxt*16384 + g*4096 + gs*512 + wid*8 + (gu>>1), pair);
      }
    }
    asm volatile("s_waitcnt vmcnt(0)" ::: "memory");
    __syncthreads();
    if (tid == 0)
      ASTORE32(flags + g*64 + wid, t+1);
    if (tid < 128) {
      if ((t & 3) == 0)
        out_pack[((size_t)(t>>2)*32 + g*8 + gs)*1024 + eu] = pk_out;
    }
  }
}

// ---------------- L1 2-group sample-split GRU: 256 WGs x 512 thr, 8 units/WG ----------------
// Group g=wg>>7 owns samples [g*16,g*16+16); wid=wg&127 owns units [wid*8,wid*8+8).
// Fused K=1024 tiles: ZRX=[Wxz8|Wxr8], ZRH=[Whz8|Whr8], XHH=[Wxh8|Whh8] (x-pass keeps
// left 8 cols, h-pass right 8). hi plane (96KB) LDS; lo plane global/L2.
// Per-WG h ingest = 32 KB/step -> aggregate 8 MB/step.
// Sync / publish / flags verbatim from R13-verified gru8s.
__global__ __launch_bounds__(512, 1)
void gru8L1_persist(const u32* __restrict__ xin,
                    const u16* __restrict__ imgH, const u16* __restrict__ imgL,
                    const float* __restrict__ bias,
                    u32* hbuf, int* flags, u32* out_pack)
{
  __shared__ u16 WIMG[49152];        // hi plane, 98,304 B
  __shared__ float exch[8*16*33];    // 16,896 B
  __shared__ float harr[128];        // 16 samples x 8 units
  __shared__ int hready[32];         // [0]=units 0..511 (wids 0-63), [16]=512..1023

  const int tid  = threadIdx.x;
  const int wg   = blockIdx.x;
  const int g    = wg >> 7;
  const int wid  = wg & 127;
  const int lane = tid & 63;
  const int wave = tid >> 6;         // = kq (0..7), K-eighth of 1024
  const int kq   = wave;
  const int lo16 = lane & 15, hi16 = lane >> 4;
  const int lane_off = hi16*128 + lo16*8;
  const int hsel = (kq >= 4) ? 16 : 0;

  { // stage hi plane: 49152 u16 = 12288 u64 (count = elems/4)
    const u64* sH = (const u64*)(imgH + (size_t)wid*49152);
    u64* dH = (u64*)WIMG;
    for (int i = tid; i < 12288; i += 512) dH[i] = sH[i];
    if (tid < 32) hready[tid] = 0;
    if (tid < 128){   // fp32 h state: sample g*16+(tid>>3), unit wid*8+(tid&7) — slot0 zeros
      u16 hv = ((const u16*)hbuf)[g*16384 + (tid>>3)*1024 + wid*8 + (tid&7)];
      harr[tid] = bf2f((u32)hv);
    }
  }
  __syncthreads();

  // fragment pointers: LDS hi, global lo. kq covers blks [kq*4, kq*4+4).
  const u16* gLo   = imgL + (size_t)wid*49152;
  const u16* zrx_h = &WIMG[kq*2048 + lane_off];          const u16* zrx_l = gLo + kq*2048 + lane_off;
  const u16* zrh_h = &WIMG[16384 + kq*2048 + lane_off];  const u16* zrh_l = gLo + 16384 + kq*2048 + lane_off;
  const u16* xhh_h = &WIMG[32768 + kq*2048 + lane_off];  const u16* xhh_l = gLo + 32768 + kq*2048 + lane_off;

  const int gs = tid >> 3, gu = tid & 7, eu = wid*8 + gu;   // gate: sample(0..15) / unit
  const float zb  = bias[eu]        + bias[3072 + eu];
  const float rbv = bias[1024 + eu] + bias[4096 + eu];
  const float hxb = bias[2048 + eu];
  const float hrb = bias[5120 + eu];

  for (int t = 0; t < 250; ++t) {
    const int cur = t & 1, nxt = cur ^ 1;
    f32x4 aZR = (f32x4){0.f,0.f,0.f,0.f};
    f32x4 aXH = (f32x4){0.f,0.f,0.f,0.f};
    f32x4 aHR = (f32x4){0.f,0.f,0.f,0.f};
    { // x-pass (h-independent): sub_pack rows g*16+lo16, k in [kq*128, kq*128+128)
      const u32* xrow = xin + ((size_t)t*32 + g*16 + lo16)*1024 + kq*128 + hi16*8;
#pragma unroll
      for (int kt = 0; kt < 4; ++kt) {
        uint4 a0 = *(const uint4*)(xrow + kt*32);
        uint4 a1 = *(const uint4*)(xrow + kt*32 + 4);
        short8 ahi, alo; unpack8(a0, a1, ahi, alo);
        short8 bzh = *(const short8*)(zrx_h + kt*512), bzl = *(const short8*)(zrx_l + kt*512);
        short8 bxh = *(const short8*)(xhh_h + kt*512), bxl = *(const short8*)(xhh_l + kt*512);
        aZR = MFMA(ahi,bzh,aZR); aZR = MFMA(alo,bzh,aZR); aZR = MFMA(ahi,bzl,aZR);
        aXH = MFMA(ahi,bxh,aXH); aXH = MFMA(alo,bxh,aXH); aXH = MFMA(ahi,bxl,aXH);
      }
    }
    // split-release wait: wave0 polls group's wids 0..63, wave1 wids 64..127.
    if (t > 0) {
      if (wave == 0) {
        int f0;
        do { f0 = ALOAD32(flags + g*128 + lane); } while (__all(f0 >= t) == 0);
        asm volatile("" ::: "memory");
        if (lane == 0) ((volatile int*)hready)[0] = t;
      } else if (wave == 1) {
        int f1;
        do { f1 = ALOAD32(flags + g*128 + 64 + lane); } while (__all(f1 >= t) == 0);
        asm volatile("" ::: "memory");
        if (lane == 0) ((volatile int*)hready)[16] = t;
      }
      while (((volatile int*)hready)[hsel] < t) { }
      asm volatile("" ::: "memory");   // pin h loads behind the release
    }
    { // h-pass: group's 16 bf16-hi rows; 4x dwordx4 LLC loads
      const u32* hrow = hbuf + cur*16384 + g*8192 + lo16*512 + kq*64 + hi16*4;
      u32x4 qa, qb, qc, qd;
      asm volatile(
        "global_load_dwordx4 %0, %4, off sc0 sc1\n\t"
        "global_load_dwordx4 %1, %4, off offset:64 sc0 sc1\n\t"
        "global_load_dwordx4 %2, %4, off offset:128 sc0 sc1\n\t"
        "global_load_dwordx4 %3, %4, off offset:192 sc0 sc1\n\t"
        "s_waitcnt vmcnt(0)"
        : "=&v"(qa), "=&v"(qb), "=&v"(qc), "=&v"(qd)
        : "v"(hrow)
        : "memory");
      short8 ah0, ah1, ah2, ah3;
      unpackh4(qa, ah0); unpackh4(qb, ah1); unpackh4(qc, ah2); unpackh4(qd, ah3);
#pragma unroll
      for (int kt = 0; kt < 4; ++kt){
        short8 ah = (kt==0)?ah0:(kt==1)?ah1:(kt==2)?ah2:ah3;
        short8 bzh = *(const short8*)(zrh_h + kt*512), bzl = *(const short8*)(zrh_l + kt*512);
        short8 bhh = *(const short8*)(xhh_h + kt*512), bhl = *(const short8*)(xhh_l + kt*512);
        aZR = MFMA(ah,bzh,aZR); aZR = MFMA(ah,bzl,aZR);
        aHR = MFMA(ah,bhh,aHR); aHR = MFMA(ah,bhl,aHR);
      }
    }
    { // exchange: 16 rows (samples); cols 0-15 = z|r, 16-23 = xh (lo16<8), 24-31 = rh
#pragma unroll
      for (int r4 = 0; r4 < 4; ++r4){
        float* e = &exch[(kq*16 + hi16*4 + r4)*33];
        e[lo16]      = aZR[r4];
        e[16 + lo16] = (lo16 < 8) ? aXH[r4] : aHR[r4];
      }
    }
    __syncthreads();                       // S1: exch ready (all flags >= t joined)
    u32 pk_out = 0;
    if (tid < 128) { // gates: one (sample, unit) per thread
      float zp=0.f, rp=0.f, xh=0.f, rh=0.f;
#pragma unroll
      for (int k8 = 0; k8 < 8; ++k8){
        const float* e = &exch[(k8*16 + gs)*33];
        zp += e[gu]; rp += e[8+gu]; xh += e[16+gu]; rh += e[24+gu];
      }
      float z = 1.f/(1.f + __expf(-(zp + zb)));
      float r = 1.f/(1.f + __expf(-(rp + rbv)));
      float pre = xh + hxb + r*(rh + hrb);
      float ex = __expf(-2.f*fabsf(pre));
      float th = (1.f - ex)/(1.f + ex);
      float hh = copysignf(th, pre);
      float hn = z*harr[tid] + (1.f - z)*hh;
      harr[tid] = hn;
      pk_out = pack_f(hn);
      // h broadcast: bf16-hi, two adjacent units per u32, even lane stores
      int pk16 = (int)(pk_out & 0xffffu);
      int prt  = __shfl_xor(pk16, 1);
      if ((tid & 1) == 0) {
        u32 pair = (u32)pk16 | ((u32)prt << 16);
        ASTORE32(hbuf + nxt*16384 + g*8192 + gs*512 + wid*4 + (gu>>1), pair);
      }
    }
    asm volatile("s_waitcnt vmcnt(0)" ::: "memory");   // h stores acked at LLC
    __syncthreads();                                   // S2
    if (tid == 0)
      ASTORE32(flags + g*128 + wid, t+1);
    if (tid < 128) {    // out2 store off the publish path (packed {hi,lo})
      out_pack[((size_t)t*32 + g*16 + gs)*1024 + eu] = pk_out;
    }
  }
}

// ---------------- final dense head ----------------
__global__ __launch_bounds__(256, 1)
void dense_k(const u32* __restrict__ h2, const float* __restrict__ W,
             const float* __restrict__ bias, float* __restrict__ out){
  __shared__ float rows[32*1025];
  const int ts = blockIdx.x;
  const u32* src = h2 + (size_t)ts*32768;
  for (int i = threadIdx.x; i < 32768; i += 256){
    u32 p = src[i];
    rows[(i>>10)*1025 + (i&1023)] = bf2f(p & 0xffffu) + bf2f(p >> 16);
  }
  __syncthreads();
  const int b = threadIdx.x >> 3, cg = threadIdx.x & 7;
  float acc[6] = {0.f,0.f,0.f,0.f,0.f,0.f};
  for (int k = 0; k < 1024; ++k){
    float hv = rows[b*1025 + k];
    const float* wr = W + k*41;
#pragma unroll
    for (int j = 0; j < 6; ++j){ int c = cg + 8*j; if (c < 41) acc[j] += hv*wr[c]; }
  }
#pragma unroll
  for (int j = 0; j < 6; ++j){
    int c = cg + 8*j;
    if (c < 41) out[((size_t)b*250 + ts)*41 + c] = acc[j] + bias[c];
  }
}

// ---------------- launch ----------------
extern "C" void kernel_launch(void* const* d_in, const int* in_sizes, int n_in,
                              void* d_out, int out_size, void* d_ws, size_t ws_size,
                              hipStream_t stream) {
  const float* x      = (const float*)d_in[0];
  const float* conv_w = (const float*)d_in[1];
  const float* h0i    = (const float*)d_in[2];
  const float* w0x    = (const float*)d_in[3];
  const float* w0h    = (const float*)d_in[4];
  const float* b0     = (const float*)d_in[5];
  const float* w1x    = (const float*)d_in[6];
  const float* w1h    = (const float*)d_in[7];
  const float* b1     = (const float*)d_in[8];
  const float* dw     = (const float*)d_in[9];
  const float* db     = (const float*)d_in[10];
  float* outp = (float*)d_out;

  if (ws_size < WS_NEED) return;  // workspace too small: leave output poisoned

  char* ws = (char*)d_ws;
  u32* y_pack   = (u32*)(ws + OFF_Y);
  u32* out2     = (u32*)(ws + OFF_Y);      // reuse after y_pack is dead
  u32* sub_pack = (u32*)(ws + OFF_SUB);
  u16* w0iH = (u16*)(ws + OFF_W0IH); u16* w0iL = (u16*)(ws + OFF_W0IL);
  u16* w1iH = (u16*)(ws + OFF_W1IH); u16* w1iL = (u16*)(ws + OFF_W1IL);
  u32* hb0 = (u32*)(ws + OFF_HB0);
  u32* hb1 = (u32*)(ws + OFF_HB1);
  int* fl0 = (int*)(ws + OFF_FL0);
  int* fl1 = (int*)(ws + OFF_FL1);

  init_state<<<64, 512, 0, stream>>>(h0i, hb0, hb1, fl0, fl1);
  build_w0img<<<2048, 256, 0, stream>>>(w0x, w0h, w0iH, w0iL);
  build_w1img<<<2048, 256, 0, stream>>>(w1x, w1h, w1iH, w1iL);
  conv_pack<<<4096, 256, 0, stream>>>(x, conv_w, y_pack);

  gru16_persist<<<256, 512, 0, stream>>>(y_pack, w0iH, w0iL, b0, hb0, fl0, sub_pack);
  gru8L1_persist<<<256, 512, 0, stream>>>(sub_pack, w1iH, w1iL, b1, hb1, fl1, out2);

  dense_k<<<250, 256, 0, stream>>>(out2, dw, db, outp);
}